// Round 1
// 4321.762 us; speedup vs baseline: 1.8290x; 1.8290x over previous
//
#include <hip/hip_runtime.h>
#include <math.h>

// SynchronGRU R8: kill the per-step weight stream (was ~206 GB of L2 reads =
// the 73% idle time; VALUBusy only 26.6%).
//  - 512 threads (8 waves, 1 block/CU via 144 KB LDS, 2 waves/SIMD -> 256 VGPR).
//  - rec_k register-resident: thread (kq in 0..3, c in 0..127) holds
//    rec_k[32kq..32kq+31][3c..3c+2] = 96 floats, loaded once per layer.
//  - x-projection hoisted out of the recurrence: computed in chunks of 8
//    steps (W_x streamed from L2 once per 8 steps instead of every step),
//    k-partials reduced via LDS into xg[8][2][384].
//  - per step: h-dot uses only registers + LDS broadcasts (192 FMA/thread),
//    then 256 gate threads combine partials. 2 barriers/step.
//  - asm launder kept ONLY on W_x inside the chunk loop: prevents LICM from
//    hoisting 96 loop-invariant W_x loads on top of the 96 resident rec_k
//    weights (that would spill; R1-R5 lesson).

namespace {

constexpr int kB = 512;
constexpr int kT = 256;
constexpr int kF = 8;
constexpr int kU = 128;
constexpr int kG = 384;   // 3*U, gate order [z, r, h]
constexpr int kL = 8;
constexpr int kRows = 2;  // batch rows per block
constexpr int kThreads = 512;  // 8 waves
constexpr int kSt = 8;         // time-steps per x-projection chunk

// LDS layout (floats)
constexpr int kOffXg     = 0;                  // [8t][2r][384]      = 6144
constexpr int kOffXpart  = 6144;               // [4kq][8t][2r][384] = 24576
constexpr int kOffXstage = 6144 + 24576;       // [2r][8t][128]      = 2048  (30720)
constexpr int kOffHbuf   = kOffXstage + 2048;  // [2r][128]          = 256   (32768)
constexpr int kOffPacc   = kOffHbuf + 256;     // [4kq][2r][384]     = 3072  (33024)
constexpr int kOffBiasx  = kOffPacc + 3072;    // [384]                      (36096)
constexpr int kOffBiash  = kOffBiasx + 384;    // [384]                      (36480)
constexpr int kSmemFloats = kOffBiash + 384;   // 36864 floats = 144 KB
static_assert(kSmemFloats * 4 <= 160 * 1024, "LDS budget");

// x-projection partial chunk: 4 weight rows x (8t x 2r) against resident xa.
// k4 may be a runtime loop index; all xa indices stay compile-time static.
#define X2_CHUNK(k4)                                                          \
    {                                                                         \
        float w[4][3];                                                        \
        _Pragma("unroll")                                                     \
        for (int j = 0; j < 4; ++j) {                                         \
            const float* wp = Wxp + (size_t)(32 * kq + 4 * (k4) + j) * kG + 3 * c; \
            w[j][0] = wp[0]; w[j][1] = wp[1]; w[j][2] = wp[2];                \
        }                                                                     \
        _Pragma("unroll")                                                     \
        for (int tt = 0; tt < kSt; ++tt) {                                    \
            _Pragma("unroll")                                                 \
            for (int r = 0; r < 2; ++r) {                                     \
                const float4 xv = *(const float4*)&xstage[(r * kSt + tt) * kU + 32 * kq + 4 * (k4)]; \
                const float xvv[4] = {xv.x, xv.y, xv.z, xv.w};                \
                _Pragma("unroll")                                             \
                for (int j = 0; j < 4; ++j) {                                 \
                    xa[tt][r][0] += w[j][0] * xvv[j];                         \
                    xa[tt][r][1] += w[j][1] * xvv[j];                         \
                    xa[tt][r][2] += w[j][2] * xvv[j];                         \
                }                                                             \
            }                                                                 \
        }                                                                     \
    }

// one k-quad of the recurrent dot: register weights x LDS-broadcast h.
#define HDOT(k4)                                                              \
    {                                                                         \
        const float4 h0 = h0p[(k4)];                                          \
        const float4 h1 = h1p[(k4)];                                          \
        const float hv0[4] = {h0.x, h0.y, h0.z, h0.w};                        \
        const float hv1[4] = {h1.x, h1.y, h1.z, h1.w};                        \
        _Pragma("unroll")                                                     \
        for (int j = 0; j < 4; ++j) {                                         \
            a00 += wk[4 * (k4) + j][0] * hv0[j];                              \
            a01 += wk[4 * (k4) + j][1] * hv0[j];                              \
            a02 += wk[4 * (k4) + j][2] * hv0[j];                              \
            b00 += wk[4 * (k4) + j][0] * hv1[j];                              \
            b01 += wk[4 * (k4) + j][1] * hv1[j];                              \
            b02 += wk[4 * (k4) + j][2] * hv1[j];                              \
        }                                                                     \
    }

__global__ __launch_bounds__(kThreads, 2) void gru_all(
    const float* __restrict__ xin,      // (B,T,F)
    const float* __restrict__ init_h,   // (L,B,U)
    const float* __restrict__ kernel0,  // (F,3U)
    const float* __restrict__ kernels,  // (L-1,U,3U)
    const float* __restrict__ rec_k,    // (L,U,3U)
    const float* __restrict__ biases,   // (L,2,3U)
    float* __restrict__ out)            // (B,T,U) seq out | (L,B,U) states
{
    __shared__ __align__(16) float smem[kSmemFloats];
    float* xg     = smem + kOffXg;
    float* xpart  = smem + kOffXpart;
    float* xstage = smem + kOffXstage;
    float* hbuf   = smem + kOffHbuf;
    float* pacc   = smem + kOffPacc;
    float* biasx  = smem + kOffBiasx;
    float* biash  = smem + kOffBiash;

    const int tid = threadIdx.x;
    const int b0  = blockIdx.x * kRows;
    const int kq  = tid >> 7;   // k-quarter 0..3
    const int c   = tid & 127;  // column triple: cols 3c..3c+2

    const int gr = (tid >> 7) & 1;  // gate-phase row  (valid tid<256)
    const int gu = tid & 127;       // gate-phase unit

    float* __restrict__ buf    = out;                        // in-place activations
    float* __restrict__ states = out + (size_t)kB * kT * kU; // final h per layer

#pragma unroll 1
    for (int l = 0; l < kL; ++l) {
        // ---- rec_k tile -> registers (once per layer) ----
        float wk[32][3];
        {
            const float* Whp = rec_k + (size_t)l * kU * kG;
#pragma unroll
            for (int i = 0; i < 32; ++i) {
                const float* p = Whp + (size_t)(32 * kq + i) * kG + 3 * c;
                wk[i][0] = p[0]; wk[i][1] = p[1]; wk[i][2] = p[2];
            }
        }
        if (tid < kG) {
            biasx[tid] = biases[l * 2 * kG + tid];
            biash[tid] = biases[l * 2 * kG + kG + tid];
        }
        if (tid < kRows * kU)
            hbuf[tid] = init_h[(size_t)l * kB * kU + (size_t)(b0 + gr) * kU + gu];
        __syncthreads();

#pragma unroll 1
        for (int t0 = 0; t0 < kT; t0 += kSt) {
            // ---- X1: stage x inputs for the next 8 steps ----
            if (l == 0) {
                if (tid < 32) {
                    const int r = tid >> 4, tt = (tid >> 1) & 7, cc = tid & 1;
                    *(float4*)&xstage[(r * kSt + tt) * kU + 4 * cc] =
                        *(const float4*)(xin + ((size_t)(b0 + r) * kT + (t0 + tt)) * kF + 4 * cc);
                }
            } else {
                const int r = tid >> 8, rest = tid & 255, tt = rest >> 5, cc = rest & 31;
                *(float4*)&xstage[(r * kSt + tt) * kU + 4 * cc] =
                    *(const float4*)(buf + ((size_t)(b0 + r) * kT + (t0 + tt)) * kU + 4 * cc);
            }
            __syncthreads();

            // ---- X2: x-projection k-partials (W_x streamed once per 8 steps) ----
            {
                float xa[kSt][2][3];
#pragma unroll
                for (int tt = 0; tt < kSt; ++tt)
#pragma unroll
                    for (int r = 0; r < 2; ++r) {
                        xa[tt][r][0] = 0.f; xa[tt][r][1] = 0.f; xa[tt][r][2] = 0.f;
                    }
                if (l == 0) {
                    const float* Wxp = kernel0;
                    asm volatile("" : "+v"(Wxp));  // no LICM hoist across t0 loop
                    if (kq == 0) {                 // K = kF = 8: rows 0..7 only
#pragma unroll
                        for (int k4 = 0; k4 < 2; ++k4) { X2_CHUNK(k4) }
                    }
                } else {
                    const float* Wxp = kernels + (size_t)(l - 1) * kU * kG;
                    asm volatile("" : "+v"(Wxp));  // no LICM hoist across t0 loop
#pragma unroll 2
                    for (int k4 = 0; k4 < 8; ++k4) { X2_CHUNK(k4) }
                }
#pragma unroll
                for (int tt = 0; tt < kSt; ++tt)
#pragma unroll
                    for (int r = 0; r < 2; ++r) {
                        float* p = xpart + (size_t)((kq * kSt + tt) * 2 + r) * kG + 3 * c;
                        p[0] = xa[tt][r][0]; p[1] = xa[tt][r][1]; p[2] = xa[tt][r][2];
                    }
            }
            __syncthreads();

            // ---- X3: reduce 4 k-partials -> xg (l==0 partials for kq>0 are 0) ----
#pragma unroll
            for (int j = 0; j < 12; ++j) {
                const int i = tid + j * kThreads;
                xg[i] = xpart[i] + xpart[6144 + i] + xpart[12288 + i] + xpart[18432 + i];
            }
            __syncthreads();

            // ---- 8 recurrence steps: registers + LDS only ----
#pragma unroll 1
            for (int tt = 0; tt < kSt; ++tt) {
                {
                    float a00 = 0.f, a01 = 0.f, a02 = 0.f;
                    float b00 = 0.f, b01 = 0.f, b02 = 0.f;
                    const float4* h0p = (const float4*)&hbuf[32 * kq];
                    const float4* h1p = (const float4*)&hbuf[kU + 32 * kq];
                    HDOT(0) HDOT(1) HDOT(2) HDOT(3)
                    HDOT(4) HDOT(5) HDOT(6) HDOT(7)
                    float* p0 = pacc + (size_t)(kq * 2 + 0) * kG + 3 * c;
                    float* p1 = pacc + (size_t)(kq * 2 + 1) * kG + 3 * c;
                    p0[0] = a00; p0[1] = a01; p0[2] = a02;
                    p1[0] = b00; p1[1] = b01; p1[2] = b02;
                }
                __syncthreads();

                if (tid < kRows * kU) {
                    const float* xgp = xg + (size_t)(tt * 2 + gr) * kG;
                    float xz = biasx[gu]          + xgp[gu];
                    float xr = biasx[kU + gu]     + xgp[kU + gu];
                    float xh = biasx[2 * kU + gu] + xgp[2 * kU + gu];
                    float hz = biash[gu], hr = biash[kU + gu], hp = biash[2 * kU + gu];
#pragma unroll
                    for (int k2 = 0; k2 < 4; ++k2) {
                        const float* ph = pacc + (size_t)(k2 * 2 + gr) * kG;
                        hz += ph[gu]; hr += ph[kU + gu]; hp += ph[2 * kU + gu];
                    }
                    const float z  = 1.f / (1.f + __expf(-(xz + hz)));
                    const float rg = 1.f / (1.f + __expf(-(xr + hr)));
                    const float hh = tanhf(xh + rg * hp);
                    const float h  = z * hbuf[gr * kU + gu] + (1.f - z) * hh;
                    hbuf[gr * kU + gu] = h;
                    buf[((size_t)(b0 + gr) * kT + (t0 + tt)) * kU + gu] = h;
                }
                __syncthreads();
            }
        }

        // ---- final state of this layer ----
        if (tid < kRows * kU)
            states[(size_t)l * kB * kU + (size_t)(b0 + gr) * kU + gu] = hbuf[tid];
        __syncthreads();
    }
}

}  // namespace

extern "C" void kernel_launch(void* const* d_in, const int* in_sizes, int n_in,
                              void* d_out, int out_size, void* d_ws, size_t ws_size,
                              hipStream_t stream) {
    const float* xin     = (const float*)d_in[0];
    const float* init_h  = (const float*)d_in[1];
    const float* kernel0 = (const float*)d_in[2];
    const float* kernels = (const float*)d_in[3];
    const float* rec_k   = (const float*)d_in[4];
    const float* biases  = (const float*)d_in[5];
    float* out = (float*)d_out;

    dim3 grid(kB / kRows);   // 256 blocks -> 1 per CU (144 KB LDS enforces)
    dim3 block(kThreads);    // 512 threads = 8 waves, 2 per SIMD
    gru_all<<<grid, block, 0, stream>>>(xin, init_h, kernel0, kernels, rec_k, biases, out);
}

// Round 2
// 3750.854 us; speedup vs baseline: 2.1073x; 1.1522x over previous
//
#include <hip/hip_runtime.h>
#include <math.h>

// SynchronGRU R9: BOTH weight matrices register-resident.
// R8 (4.94 ms) removed the per-step rec_k stream but still streamed W_x from
// L2 every 8 steps through a 96 KB LDS partial buffer (xpart) + extra reduce
// phase, and thrashed registers (wk 96 + xa 48 live > 128 VGPR alloc).
// R9: 512 threads, __launch_bounds__(512,2) -> 256 VGPR budget. Each thread
// holds wk[96] + wx[96] (rec + input weights for cols {c,128+c,256+c}, k-rows
// 32kq..32kq+31) = 192 resident floats. Per step: ONE fused phase, 384 FMA
// (x-side + h-side), z/r partials combined in-register (algebra allows),
// candidate kept split (r multiplies only the h side). No W_x stream, no
// xpart, no X3 reduce. LDS 25.6 KB. l==0 (F=8) handled branch-free via
// zero-filled wx rows + zeroed xstage.
// R1-R5's "register weights spill" was at 768 threads (~170 VGPR budget);
// 230 live < 256 here.

namespace {

constexpr int kB = 512;
constexpr int kT = 256;
constexpr int kF = 8;
constexpr int kU = 128;
constexpr int kG = 384;   // 3*U, gate order [z, r, h]
constexpr int kL = 8;
constexpr int kRows = 2;       // batch rows per block
constexpr int kThreads = 512;  // 8 waves
constexpr int kSt = 8;         // time-steps per x staging chunk

// LDS layout (floats)
constexpr int kOffXstage = 0;                  // [2r][8t][128] = 2048
constexpr int kOffHbuf   = 2048;               // [2r][128]     = 256
constexpr int kOffPacc   = 2304;               // [4kq][2r][512] = 4096
constexpr int kSmemFloats = 2304 + 4096;       // 6400 floats = 25.6 KB
static_assert(kSmemFloats * 4 <= 160 * 1024, "LDS budget");

__device__ __forceinline__ float frcp(float x) { return __builtin_amdgcn_rcpf(x); }

__global__ __launch_bounds__(kThreads, 2) void gru_all(
    const float* __restrict__ xin,      // (B,T,F)
    const float* __restrict__ init_h,   // (L,B,U)
    const float* __restrict__ kernel0,  // (F,3U)
    const float* __restrict__ kernels,  // (L-1,U,3U)
    const float* __restrict__ rec_k,    // (L,U,3U)
    const float* __restrict__ biases,   // (L,2,3U)
    float* __restrict__ out)            // (B,T,U) seq out | (L,B,U) states
{
    __shared__ __align__(16) float smem[kSmemFloats];
    float* xstage = smem + kOffXstage;
    float* hbuf   = smem + kOffHbuf;
    float* pacc   = smem + kOffPacc;

    const int tid = threadIdx.x;
    const int b0  = blockIdx.x * kRows;
    const int kq  = tid >> 7;   // k-quarter: k in [32kq, 32kq+32)
    const int c   = tid & 127;  // owns cols c (z), 128+c (r), 256+c (cand)

    const int gr = (tid >> 7) & 1;  // gate-phase row  (valid tid<256)
    const int gu = tid & 127;       // gate-phase unit

    float* __restrict__ buf    = out;                        // in-place activations
    float* __restrict__ states = out + (size_t)kB * kT * kU; // final h per layer

    // zero xstage once: layer 0 only writes cols 0..7 (F=8); the rest must be
    // 0 so the branch-free 128-k x-loop (with zero wx rows) is exact.
#pragma unroll
    for (int j = 0; j < 4; ++j) xstage[tid + j * kThreads] = 0.f;

#pragma unroll 1
    for (int l = 0; l < kL; ++l) {
        // ---- weights -> registers (once per layer), coalesced per (i,gate) ----
        float wkz[32], wkr[32], wkh[32];  // rec_k rows 32kq+i, col {c,128+c,256+c}
        float wxz[32], wxr[32], wxh[32];  // input kernel, same tile
        {
            const float* Wh = rec_k + (size_t)l * kU * kG;
#pragma unroll
            for (int i = 0; i < 32; ++i) {
                const float* p = Wh + (size_t)(32 * kq + i) * kG;
                wkz[i] = p[c]; wkr[i] = p[kU + c]; wkh[i] = p[2 * kU + c];
            }
        }
        if (l == 0) {
#pragma unroll
            for (int i = 0; i < 32; ++i) { wxz[i] = 0.f; wxr[i] = 0.f; wxh[i] = 0.f; }
            if (kq == 0) {
#pragma unroll
                for (int i = 0; i < kF; ++i) {
                    const float* p = kernel0 + (size_t)i * kG;
                    wxz[i] = p[c]; wxr[i] = p[kU + c]; wxh[i] = p[2 * kU + c];
                }
            }
        } else {
            const float* Wx = kernels + (size_t)(l - 1) * kU * kG;
#pragma unroll
            for (int i = 0; i < 32; ++i) {
                const float* p = Wx + (size_t)(32 * kq + i) * kG;
                wxz[i] = p[c]; wxr[i] = p[kU + c]; wxh[i] = p[2 * kU + c];
            }
        }

        // ---- per-layer gate-thread state: biases + h in registers ----
        float bz = 0.f, br = 0.f, bxh = 0.f, bhh = 0.f, hreg = 0.f;
        if (tid < kRows * kU) {
            const float* bp = biases + (size_t)l * 2 * kG;
            bz  = bp[gu] + bp[kG + gu];              // x-bias + h-bias (z)
            br  = bp[kU + gu] + bp[kG + kU + gu];    // (r)
            bxh = bp[2 * kU + gu];                   // x-bias (candidate)
            bhh = bp[kG + 2 * kU + gu];              // h-bias (candidate, inside r*)
            hreg = init_h[(size_t)l * kB * kU + (size_t)(b0 + gr) * kU + gu];
            hbuf[tid] = hreg;
        }
        __syncthreads();

#pragma unroll 1
        for (int t0 = 0; t0 < kT; t0 += kSt) {
            // ---- X1: stage x for the next 8 steps ----
            if (l == 0) {
                if (tid < 32) {
                    const int r = tid >> 4, tt = (tid >> 1) & 7, cc = tid & 1;
                    *(float4*)&xstage[(r * kSt + tt) * kU + 4 * cc] =
                        *(const float4*)(xin + ((size_t)(b0 + r) * kT + (t0 + tt)) * kF + 4 * cc);
                }
            } else {
                const int r = tid >> 8, rest = tid & 255, tt = rest >> 5, cc = rest & 31;
                *(float4*)&xstage[(r * kSt + tt) * kU + 4 * cc] =
                    *(const float4*)(buf + ((size_t)(b0 + r) * kT + (t0 + tt)) * kU + 4 * cc);
            }
            __syncthreads();

            // ---- 8 recurrence steps: pure registers + LDS ----
#pragma unroll 1
            for (int tt = 0; tt < kSt; ++tt) {
                {
                    const float4* xs0 = (const float4*)&xstage[(0 * kSt + tt) * kU + 32 * kq];
                    const float4* xs1 = (const float4*)&xstage[(1 * kSt + tt) * kU + 32 * kq];
                    const float4* hs0 = (const float4*)&hbuf[32 * kq];
                    const float4* hs1 = (const float4*)&hbuf[kU + 32 * kq];
                    float az0 = 0.f, ar0 = 0.f, ahh0 = 0.f, axh0 = 0.f;
                    float az1 = 0.f, ar1 = 0.f, ahh1 = 0.f, axh1 = 0.f;
#pragma unroll
                    for (int k4 = 0; k4 < 8; ++k4) {
                        const float4 xv0 = xs0[k4], xv1 = xs1[k4];
                        const float4 hv0 = hs0[k4], hv1 = hs1[k4];
                        const float x0[4] = {xv0.x, xv0.y, xv0.z, xv0.w};
                        const float x1[4] = {xv1.x, xv1.y, xv1.z, xv1.w};
                        const float h0[4] = {hv0.x, hv0.y, hv0.z, hv0.w};
                        const float h1[4] = {hv1.x, hv1.y, hv1.z, hv1.w};
#pragma unroll
                        for (int j = 0; j < 4; ++j) {
                            const int i = 4 * k4 + j;
                            az0  += wkz[i] * h0[j];  az1  += wkz[i] * h1[j];
                            ar0  += wkr[i] * h0[j];  ar1  += wkr[i] * h1[j];
                            ahh0 += wkh[i] * h0[j];  ahh1 += wkh[i] * h1[j];
                            az0  += wxz[i] * x0[j];  az1  += wxz[i] * x1[j];
                            ar0  += wxr[i] * x0[j];  ar1  += wxr[i] * x1[j];
                            axh0 += wxh[i] * x0[j];  axh1 += wxh[i] * x1[j];
                        }
                    }
                    // partials: [4kq][2r][512]: 0..127 z(x+h), 128..255 r(x+h),
                    // 256..383 cand-h, 384..511 cand-x
                    float* p0 = pacc + (size_t)(kq * 2 + 0) * 512;
                    float* p1 = pacc + (size_t)(kq * 2 + 1) * 512;
                    p0[c] = az0; p0[kU + c] = ar0; p0[2 * kU + c] = ahh0; p0[3 * kU + c] = axh0;
                    p1[c] = az1; p1[kU + c] = ar1; p1[2 * kU + c] = ahh1; p1[3 * kU + c] = axh1;
                }
                __syncthreads();

                // ---- gates: threads 0..255 = (row, unit) ----
                if (tid < kRows * kU) {
                    const float* p = pacc + (size_t)gr * 512;  // + kq*1024
                    const float sz  = p[gu]            + p[1024 + gu]            + p[2048 + gu]            + p[3072 + gu];
                    const float sr  = p[kU + gu]       + p[1024 + kU + gu]       + p[2048 + kU + gu]       + p[3072 + kU + gu];
                    const float shh = p[2 * kU + gu]   + p[1024 + 2 * kU + gu]   + p[2048 + 2 * kU + gu]   + p[3072 + 2 * kU + gu];
                    const float sxh = p[3 * kU + gu]   + p[1024 + 3 * kU + gu]   + p[2048 + 3 * kU + gu]   + p[3072 + 3 * kU + gu];
                    const float z  = frcp(1.f + __expf(-(sz + bz)));
                    const float rg = frcp(1.f + __expf(-(sr + br)));
                    const float ta = sxh + bxh + rg * (shh + bhh);
                    const float hh = 1.f - 2.f * frcp(1.f + __expf(2.f * ta));  // tanh(ta)
                    const float h  = z * hreg + (1.f - z) * hh;
                    hreg = h;
                    hbuf[gr * kU + gu] = h;
                    buf[((size_t)(b0 + gr) * kT + (t0 + tt)) * kU + gu] = h;
                }
                __syncthreads();
            }
        }

        // ---- final state of this layer ----
        if (tid < kRows * kU)
            states[(size_t)l * kB * kU + (size_t)(b0 + gr) * kU + gu] = hreg;
        __syncthreads();
    }
}

}  // namespace

extern "C" void kernel_launch(void* const* d_in, const int* in_sizes, int n_in,
                              void* d_out, int out_size, void* d_ws, size_t ws_size,
                              hipStream_t stream) {
    const float* xin     = (const float*)d_in[0];
    const float* init_h  = (const float*)d_in[1];
    const float* kernel0 = (const float*)d_in[2];
    const float* kernels = (const float*)d_in[3];
    const float* rec_k   = (const float*)d_in[4];
    const float* biases  = (const float*)d_in[5];
    float* out = (float*)d_out;

    dim3 grid(kB / kRows);   // 256 blocks, 1 per CU (8 waves @ 256 VGPR)
    dim3 block(kThreads);    // 512 threads = 8 waves, 2 per SIMD
    gru_all<<<grid, block, 0, stream>>>(xin, init_h, kernel0, kernels, rec_k, biases, out);
}